// Round 1
// baseline (1068.699 us; speedup 1.0000x reference)
//
#include <hip/hip_runtime.h>

// Problem constants (from reference setup_inputs)
#define B_  4
#define H_  64
#define W_  2650
#define C_  64
#define N_  680000
#define THR_ 0.5f

// One 64-lane wave per point. lane = feature channel.
// out layout (tuple concat): out[N][69] (points[5] ++ feats[64], masked), then mask[N].
__global__ __launch_bounds__(256) void PointGather_78915729097542_kernel(
    const float* __restrict__ points,      // [N,5]  col0 = batch idx (float)
    const int*   __restrict__ ri,          // [N,2]  (row, col)
    const float* __restrict__ seg,         // [B,H,W]
    const float* __restrict__ feat,        // [B,C,H,W]
    float* __restrict__ out,               // [N,69]
    float* __restrict__ mask_out)          // [N]
{
    const int HW   = H_ * W_;
    const int lane = threadIdx.x & 63;
    const int pt   = blockIdx.x * 4 + (threadIdx.x >> 6);   // 4 waves / 256-thread block
    if (pt >= N_) return;

    // Per-point scalars: same address across the wave -> broadcast from L1.
    const int b = (int)points[(size_t)pt * 5];
    const int r = ri[(size_t)pt * 2];
    const int c = ri[(size_t)pt * 2 + 1];

    float pv = 0.0f;
    if (lane < 5) pv = points[(size_t)pt * 5 + lane];

    const int   rc   = r * W_ + c;
    const int   sidx = b * HW + rc;
    const float m    = (seg[sidx] >= THR_) ? 1.0f : 0.0f;

    // Channel gather: lane ch reads feat[b, ch, r, c]. Strided across lanes,
    // but range_features (174 MB) is L3-resident; lines reused ~16x along W.
    const float f = feat[(size_t)b * (C_ * HW) + (size_t)lane * HW + rc];

    const size_t orow = (size_t)pt * 69;
    out[orow + 5 + lane] = f * m;          // coalesced 256 B store per wave
    if (lane < 5) out[orow + lane] = pv * m;
    if (lane == 0) mask_out[pt] = m;
}

extern "C" void kernel_launch(void* const* d_in, const int* in_sizes, int n_in,
                              void* d_out, int out_size, void* d_ws, size_t ws_size,
                              hipStream_t stream) {
    const float* points = (const float*)d_in[0];   // N*5
    const int*   ri     = (const int*)  d_in[1];   // N*2
    const float* seg    = (const float*)d_in[2];   // B*H*W
    const float* feat   = (const float*)d_in[3];   // B*C*H*W

    float* out      = (float*)d_out;               // N*69
    float* mask_out = (float*)d_out + (size_t)N_ * 69;  // N

    const int blocks = (N_ + 3) / 4;  // 4 points per 256-thread block
    PointGather_78915729097542_kernel<<<blocks, 256, 0, stream>>>(
        points, ri, seg, feat, out, mask_out);
}

// Round 3
// 806.340 us; speedup vs baseline: 1.3254x; 1.3254x over previous
//
#include <hip/hip_runtime.h>

// Problem constants (from reference setup_inputs)
#define B_   4
#define H_   64
#define W_   2650
#define C_   64
#define N_   680000
#define THR_ 0.5f
#define HW_  (H_ * W_)          // 169600
#define W16_ 166                // ceil(W/16): 64B-line columns
#define M2_  (B_ * H_ * W16_)   // 42496 line-bins == 166 * 256 exactly
#define NB2_ (M2_ / 256)        // 166 scan blocks
#define CHUNK_ 16               // sorted points per wave in the main kernel

// ---- counting-sort by (b, r, c>>4): all points in a bin share the exact
// ---- same 64 feature cache lines (one per channel). --------------------

__global__ void zero_kernel(int* __restrict__ p) {
    p[blockIdx.x * 256 + threadIdx.x] = 0;       // grid == NB2_ blocks
}

__device__ __forceinline__ int bin_of(const float* pts, const int* ri, int i) {
    int b = (int)pts[(size_t)i * 5];
    int r = ri[i * 2];
    int c = ri[i * 2 + 1];
    return (b * H_ + r) * W16_ + (c >> 4);
}

__global__ void hist_kernel(const float* __restrict__ pts,
                            const int* __restrict__ ri,
                            int* __restrict__ binarr) {
    int i = blockIdx.x * 256 + threadIdx.x;
    if (i >= N_) return;
    atomicAdd(&binarr[bin_of(pts, ri, i)], 1);
}

// In-place per-block exclusive scan; block totals -> bsum.
__global__ void scan1_kernel(int* __restrict__ binarr, int* __restrict__ bsum) {
    __shared__ int lds[256];
    int t = threadIdx.x;
    int g = blockIdx.x * 256 + t;
    int v = binarr[g];
    lds[t] = v;
    __syncthreads();
    for (int off = 1; off < 256; off <<= 1) {    // Hillis-Steele inclusive
        int x = (t >= off) ? lds[t - off] : 0;
        __syncthreads();
        lds[t] += x;
        __syncthreads();
    }
    binarr[g] = lds[t] - v;                      // exclusive, in place
    if (t == 255) bsum[blockIdx.x] = lds[255];
}

// Single-block exclusive scan of the 166 block totals.
__global__ void scan2_kernel(int* __restrict__ bsum) {
    __shared__ int lds[256];
    int t = threadIdx.x;
    int v = (t < NB2_) ? bsum[t] : 0;
    lds[t] = v;
    __syncthreads();
    for (int off = 1; off < 256; off <<= 1) {
        int x = (t >= off) ? lds[t - off] : 0;
        __syncthreads();
        lds[t] += x;
        __syncthreads();
    }
    if (t < NB2_) bsum[t] = lds[t] - v;          // exclusive
}

__global__ void scan3_kernel(int* __restrict__ binarr, const int* __restrict__ bsum) {
    int g = blockIdx.x * 256 + threadIdx.x;      // grid == NB2_ blocks
    binarr[g] += bsum[blockIdx.x];
}

// Assign each point its sorted slot (consumes binarr).
__global__ void scatter_kernel(const float* __restrict__ pts,
                               const int* __restrict__ ri,
                               int* __restrict__ binarr,
                               int* __restrict__ perm) {
    int i = blockIdx.x * 256 + threadIdx.x;
    if (i >= N_) return;
    int slot = atomicAdd(&binarr[bin_of(pts, ri, i)], 1);
    perm[slot] = i;
}

// ---- main gather: one wave processes CHUNK_ consecutive points -----------
// lane = channel. perm==nullptr -> identity order (ws-too-small fallback).
__global__ __launch_bounds__(256) void gather_kernel(
    const float* __restrict__ pts,       // [N,5]
    const int*   __restrict__ ri,        // [N,2]
    const float* __restrict__ seg,       // [B,H,W]
    const float* __restrict__ feat,      // [B,C,H,W]
    const int*   __restrict__ perm,      // [N] sorted point ids, or nullptr
    float* __restrict__ out,             // [N,69]
    float* __restrict__ mask_out)        // [N]
{
    const int lane = threadIdx.x & 63;
    const int wave = blockIdx.x * 4 + (threadIdx.x >> 6);
    const size_t base = (size_t)wave * CHUNK_;

#pragma unroll
    for (int i = 0; i < CHUNK_; i++) {
        size_t pos = base + i;
        if (pos >= N_) return;                       // wave-uniform exit
        int pt = perm ? perm[pos] : (int)pos;        // broadcast load
        int b  = (int)pts[(size_t)pt * 5];
        int r  = ri[pt * 2];
        int c  = ri[pt * 2 + 1];
        int rc = r * W_ + c;

        float m = (seg[b * HW_ + rc] >= THR_) ? 1.0f : 0.0f;
        float f = feat[(size_t)b * (C_ * HW_) + (size_t)lane * HW_ + rc];
        float pv = (lane < 5) ? pts[(size_t)pt * 5 + lane] : 0.0f;

        size_t orow = (size_t)pt * 69;
        out[orow + 5 + lane] = f * m;                // 256 B contiguous store
        if (lane < 5) out[orow + lane] = pv * m;
        if (lane == 0) mask_out[pt] = m;
    }
}

// ---- launch --------------------------------------------------------------

extern "C" void kernel_launch(void* const* d_in, const int* in_sizes, int n_in,
                              void* d_out, int out_size, void* d_ws, size_t ws_size,
                              hipStream_t stream) {
    const float* points = (const float*)d_in[0];
    const int*   ri     = (const int*)  d_in[1];
    const float* seg    = (const float*)d_in[2];
    const float* feat   = (const float*)d_in[3];

    float* out      = (float*)d_out;                       // N*69
    float* mask_out = (float*)d_out + (size_t)N_ * 69;     // N

    // Workspace layout (ints): binarr[M2_] | bsum[256] | perm[N_]  ~2.9 MB
    int* binarr = (int*)d_ws;
    int* bsum   = binarr + M2_;
    int* perm   = bsum + 256;
    const size_t needed = ((size_t)M2_ + 256 + N_) * sizeof(int);
    // ws_size is constant across calls -> this branch is replay-deterministic.
    const bool use_sort = (ws_size >= needed);

    const int nblkN  = (N_ + 255) / 256;
    const int waves  = (N_ + CHUNK_ - 1) / CHUNK_;         // 42500
    const int blocks = (waves + 3) / 4;                    // 10625

    if (use_sort) {
        zero_kernel   <<<NB2_,  256, 0, stream>>>(binarr);
        hist_kernel   <<<nblkN, 256, 0, stream>>>(points, ri, binarr);
        scan1_kernel  <<<NB2_,  256, 0, stream>>>(binarr, bsum);
        scan2_kernel  <<<1,     256, 0, stream>>>(bsum);
        scan3_kernel  <<<NB2_,  256, 0, stream>>>(binarr, bsum);
        scatter_kernel<<<nblkN, 256, 0, stream>>>(points, ri, binarr, perm);
        gather_kernel <<<blocks, 256, 0, stream>>>(points, ri, seg, feat, perm,
                                                   out, mask_out);
    } else {
        gather_kernel <<<blocks, 256, 0, stream>>>(points, ri, seg, feat,
                                                   nullptr, out, mask_out);
    }
}

// Round 4
// 489.491 us; speedup vs baseline: 2.1833x; 1.6473x over previous
//
#include <hip/hip_runtime.h>

// Problem constants (from reference setup_inputs)
#define B_   4
#define H_   64
#define W_   2650
#define C_   64
#define N_   680000
#define THR_ 0.5f
#define HW_  (H_ * W_)          // 169600
#define W16_ 166                // ceil(W/16): 64B-line columns
#define M2_  (B_ * H_ * W16_)   // 42496 line-bins == 166 * 256 exactly
#define NB2_ (M2_ / 256)        // 166 scan blocks

// ---- counting-sort by (b, r, c>>4): all points in a bin share the exact
// ---- same 64 feature cache lines (one per channel). ----------------------

__global__ void zero_kernel(int* __restrict__ p) {
    p[blockIdx.x * 256 + threadIdx.x] = 0;       // grid == NB2_ blocks
}

__device__ __forceinline__ int bin_of(const float* pts, const int* ri, int i) {
    int b = (int)pts[(size_t)i * 5];
    int r = ri[i * 2];
    int c = ri[i * 2 + 1];
    return (b * H_ + r) * W16_ + (c >> 4);
}

__global__ void hist_kernel(const float* __restrict__ pts,
                            const int* __restrict__ ri,
                            int* __restrict__ binarr) {
    int i = blockIdx.x * 256 + threadIdx.x;
    if (i >= N_) return;
    atomicAdd(&binarr[bin_of(pts, ri, i)], 1);
}

// In-place per-block exclusive scan; block totals -> bsum.
__global__ void scan1_kernel(int* __restrict__ binarr, int* __restrict__ bsum) {
    __shared__ int lds[256];
    int t = threadIdx.x;
    int g = blockIdx.x * 256 + t;
    int v = binarr[g];
    lds[t] = v;
    __syncthreads();
    for (int off = 1; off < 256; off <<= 1) {    // Hillis-Steele inclusive
        int x = (t >= off) ? lds[t - off] : 0;
        __syncthreads();
        lds[t] += x;
        __syncthreads();
    }
    binarr[g] = lds[t] - v;                      // exclusive, in place
    if (t == 255) bsum[blockIdx.x] = lds[255];
}

// Single-block exclusive scan of the 166 block totals.
__global__ void scan2_kernel(int* __restrict__ bsum) {
    __shared__ int lds[256];
    int t = threadIdx.x;
    int v = (t < NB2_) ? bsum[t] : 0;
    lds[t] = v;
    __syncthreads();
    for (int off = 1; off < 256; off <<= 1) {
        int x = (t >= off) ? lds[t - off] : 0;
        __syncthreads();
        lds[t] += x;
        __syncthreads();
    }
    if (t < NB2_) bsum[t] = lds[t] - v;          // exclusive
}

__global__ void scan3_kernel(int* __restrict__ binarr, const int* __restrict__ bsum) {
    int g = blockIdx.x * 256 + threadIdx.x;      // grid == NB2_ blocks
    binarr[g] += bsum[blockIdx.x];
}

// Assign each point its sorted slot; pack {pt, c&15, mask} into the record so
// the gather kernel never touches ri or seg.
__global__ void scatter_kernel(const float* __restrict__ pts,
                               const int* __restrict__ ri,
                               const float* __restrict__ seg,
                               int* __restrict__ binarr,
                               int* __restrict__ perm) {
    int i = blockIdx.x * 256 + threadIdx.x;
    if (i >= N_) return;
    int b   = (int)pts[(size_t)i * 5];
    int r   = ri[i * 2];
    int c   = ri[i * 2 + 1];
    int bin = (b * H_ + r) * W16_ + (c >> 4);
    int m   = (seg[(size_t)b * HW_ + r * W_ + c] >= THR_) ? 1 : 0;
    int slot = atomicAdd(&binarr[bin], 1);
    perm[slot] = i | ((c & 15) << 20) | (m << 24);   // N < 2^20
}

// ---- main gather: one wave per bin, feat lines pinned in LDS -------------
// lane = channel. Lane ch stages feat[b][ch][r][col0..col0+15] once into its
// own LDS row (written & read by the same lane -> no barrier), then loops the
// bin's points reading only perm records + pts attrs.
__global__ __launch_bounds__(256) void gather_kernel(
    const float* __restrict__ pts,       // [N,5]
    const float* __restrict__ feat,      // [B,C,H,W]
    const int*   __restrict__ binarr,    // [M2_] post-scatter inclusive ends
    const int*   __restrict__ perm,      // [N] packed records
    float* __restrict__ out,             // [N,69]
    float* __restrict__ mask_out)        // [N]
{
    __shared__ float lds[4][64 * 17];    // pad 17: inner read = 2 lanes/bank (free)
    const int lane  = threadIdx.x & 63;
    const int wslot = threadIdx.x >> 6;
    const int bin   = blockIdx.x * 4 + wslot;   // grid == M2_/4 exactly

    const int end   = binarr[bin];
    const int start = (bin == 0) ? 0 : binarr[bin - 1];
    if (start == end) return;                   // wave-uniform

    const int b    = bin / (H_ * W16_);
    const int rem  = bin % (H_ * W16_);
    const int r    = rem / W16_;
    const int col0 = (rem % W16_) * 16;

    const size_t fbase = (size_t)(b * C_ + lane) * HW_ + (size_t)r * W_ + col0;
    float* dst = &lds[wslot][lane * 17];
    if (col0 + 16 <= W_) {
        // HW_, W_, col0 all even -> 8 B aligned
        const float2* s2 = (const float2*)(feat + fbase);
#pragma unroll
        for (int j = 0; j < 8; j++) {
            float2 v = s2[j];
            dst[2 * j] = v.x;
            dst[2 * j + 1] = v.y;
        }
    } else {                                    // edge bin: clamp (dups unused)
#pragma unroll
        for (int j = 0; j < 16; j++) {
            int col = col0 + j;
            if (col >= W_) col = W_ - 1;
            dst[j] = feat[(size_t)(b * C_ + lane) * HW_ + (size_t)r * W_ + col];
        }
    }

    for (int p = start; p < end; p++) {
        int rec = perm[p];                      // broadcast load
        int pt  = rec & 0xFFFFF;
        int c15 = (rec >> 20) & 15;
        float m = (float)((rec >> 24) & 1);
        float f = lds[wslot][lane * 17 + c15];

        size_t orow = (size_t)pt * 69;
        out[orow + 5 + lane] = f * m;           // 256 B contiguous store
        if (lane < 5) out[orow + lane] = pts[(size_t)pt * 5 + lane] * m;
        if (lane == 0) mask_out[pt] = m;
    }
}

// ---- fallback (identity order, from R1) — only if ws too small -----------
__global__ __launch_bounds__(256) void gather_fallback(
    const float* __restrict__ pts, const int* __restrict__ ri,
    const float* __restrict__ seg, const float* __restrict__ feat,
    float* __restrict__ out, float* __restrict__ mask_out)
{
    const int lane = threadIdx.x & 63;
    const int pt   = blockIdx.x * 4 + (threadIdx.x >> 6);
    if (pt >= N_) return;
    int b = (int)pts[(size_t)pt * 5];
    int r = ri[pt * 2], c = ri[pt * 2 + 1];
    int rc = r * W_ + c;
    float m = (seg[b * HW_ + rc] >= THR_) ? 1.0f : 0.0f;
    float f = feat[(size_t)b * (C_ * HW_) + (size_t)lane * HW_ + rc];
    size_t orow = (size_t)pt * 69;
    out[orow + 5 + lane] = f * m;
    if (lane < 5) out[orow + lane] = pts[(size_t)pt * 5 + lane] * m;
    if (lane == 0) mask_out[pt] = m;
}

// ---- launch --------------------------------------------------------------

extern "C" void kernel_launch(void* const* d_in, const int* in_sizes, int n_in,
                              void* d_out, int out_size, void* d_ws, size_t ws_size,
                              hipStream_t stream) {
    const float* points = (const float*)d_in[0];
    const int*   ri     = (const int*)  d_in[1];
    const float* seg    = (const float*)d_in[2];
    const float* feat   = (const float*)d_in[3];

    float* out      = (float*)d_out;                       // N*69
    float* mask_out = (float*)d_out + (size_t)N_ * 69;     // N

    // Workspace layout (ints): binarr[M2_] | bsum[256] | perm[N_]  ~2.9 MB
    int* binarr = (int*)d_ws;
    int* bsum   = binarr + M2_;
    int* perm   = bsum + 256;
    const size_t needed = ((size_t)M2_ + 256 + N_) * sizeof(int);
    const bool use_sort = (ws_size >= needed);   // ws_size constant -> replay-safe

    const int nblkN = (N_ + 255) / 256;

    if (use_sort) {
        zero_kernel   <<<NB2_,   256, 0, stream>>>(binarr);
        hist_kernel   <<<nblkN,  256, 0, stream>>>(points, ri, binarr);
        scan1_kernel  <<<NB2_,   256, 0, stream>>>(binarr, bsum);
        scan2_kernel  <<<1,      256, 0, stream>>>(bsum);
        scan3_kernel  <<<NB2_,   256, 0, stream>>>(binarr, bsum);
        scatter_kernel<<<nblkN,  256, 0, stream>>>(points, ri, seg, binarr, perm);
        gather_kernel <<<M2_ / 4, 256, 0, stream>>>(points, feat, binarr, perm,
                                                    out, mask_out);
    } else {
        gather_fallback<<<(N_ + 3) / 4, 256, 0, stream>>>(points, ri, seg, feat,
                                                          out, mask_out);
    }
}